// Round 2
// baseline (542.277 us; speedup 1.0000x reference)
//
#include <hip/hip_runtime.h>
#include <hip/hip_bf16.h>
#include <math.h>

#define N 8192
#define NEGV -1000000000.0f
#define EPSV 1e-05f
#define NSPLIT 8
#define CPS (N / NSPLIT)   // 1024 columns per split
#define NTILE (CPS / 64)   // 16 tiles

typedef short bf16x8 __attribute__((ext_vector_type(8)));
typedef float f32x4 __attribute__((ext_vector_type(4)));
typedef unsigned short u16;
typedef unsigned int u32;

// ---- float workspace layout ----
#define WS_SCAL 0
#define WS_H    64                        // N*64 fp32
#define WS_ST   (WS_H + N * 64)           // N
#define WS_SBI  (WS_ST + N)               // N
#define WS_DEN  (WS_SBI + N)              // NSPLIT*N
#define WS_AGG  (WS_DEN + NSPLIT * N)     // NSPLIT*N*64
#define WS_F_END (WS_AGG + NSPLIT * N * 64)
// ---- u16 (bf16) region, offsets in u16 units from (u16*)ws ----
#define WU_BASE (WS_F_END * 2)
#define WU_QB (WU_BASE)                   // N*64
#define WU_KB (WU_BASE + N * 64)          // N*64
#define WU_MB (WU_BASE + 2 * N * 64)      // N*64 (row-major, transposed later)
#define WU_MT (WU_BASE + 3 * N * 64)      // 64*N

static __device__ __forceinline__ u16 f2bf(float f) {
    __hip_bfloat16 h = __float2bfloat16(f);
    return *(u16*)&h;
}
static __device__ __forceinline__ u32 pk2(float a, float b) {
    return (u32)f2bf(a) | ((u32)f2bf(b) << 16);
}

// ---------------- Kernel A: scalar prep ----------------
__global__ void prep_k(const float* __restrict__ tc, const float* __restrict__ wg,
                       const float* __restrict__ bg, const float* __restrict__ sbias,
                       float* __restrict__ scal) {
    int j = threadIdx.x;  // 64 threads
    float v = tc[0] * wg[j] + tc[1] * wg[64 + j] + bg[j];
    float g = 1.0f / (1.0f + __expf(-v));
    for (int off = 32; off; off >>= 1) g += __shfl_xor(g, off, 64);
    if (j == 0) {
        scal[0] = 0.125f * (g * (1.0f / 64.0f));   // qscale (gate mean + 1/sqrt(64) folded)
        scal[1] = sbias[0] * (1.0f - tc[0]);        // coef
    }
}

// ---------------- Kernel B: embed (h fp32; q,k,m bf16; st, sbi) ----------------
__global__ __launch_bounds__(256) void embed_k(
    const float* __restrict__ nf, const float* __restrict__ tc,
    const float* __restrict__ w1, const float* __restrict__ b1,
    const float* __restrict__ w2, const float* __restrict__ b2,
    const float* __restrict__ wq, const float* __restrict__ bq,
    const float* __restrict__ wk, const float* __restrict__ bk,
    const float* __restrict__ wm, const float* __restrict__ bm,
    float* __restrict__ ws)
{
    const int w = threadIdx.x >> 6, lane = threadIdx.x & 63;
    const int row = blockIdx.x * 4 + w;
    __shared__ float ts[4][64], hs[4][64];
    const float qscale = ws[WS_SCAL + 0];
    const float coef   = ws[WS_SCAL + 1];
    const float f0 = nf[row * 3], f1 = nf[row * 3 + 1], f2 = nf[row * 3 + 2];
    const float t0 = tc[0], t1 = tc[1];
    float v = b1[lane];
    v = fmaf(f0, w1[lane], v);
    v = fmaf(f1, w1[64 + lane], v);
    v = fmaf(f2, w1[128 + lane], v);
    v = fmaf(t0, w1[192 + lane], v);
    v = fmaf(t1, w1[256 + lane], v);
    ts[w][lane] = fmaxf(v, 0.0f);
    __syncthreads();
    float hv = b2[lane];
    #pragma unroll 8
    for (int j = 0; j < 64; j++) hv = fmaf(ts[w][j], w2[j * 64 + lane], hv);
    hs[w][lane] = hv;
    ws[WS_H + row * 64 + lane] = hv;
    __syncthreads();
    float qv = bq[lane], kv = bk[lane], mv = bm[lane];
    #pragma unroll 4
    for (int j = 0; j < 64; j++) {
        const float hj = hs[w][j];
        qv = fmaf(hj, wq[j * 64 + lane], qv);
        kv = fmaf(hj, wk[j * 64 + lane], kv);
        mv = fmaf(hj, wm[j * 64 + lane], mv);
    }
    u16* wu = (u16*)ws;
    wu[WU_QB + row * 64 + lane] = f2bf(qv * qscale);
    wu[WU_KB + row * 64 + lane] = f2bf(kv);
    wu[WU_MB + row * 64 + lane] = f2bf(mv);
    if (lane == 0) {
        ws[WS_ST + row]  = f2;
        ws[WS_SBI + row] = f2 * coef;
    }
}

// ---------------- Kernel B2: transpose M (bf16) ----------------
// NOTE: uint4 = 16 BYTES = 8 u16 elements. Each thread moves 16 u16 (two uint4).
__global__ __launch_bounds__(256) void transp_k(float* __restrict__ ws) {
    const u16* mb = (const u16*)ws + WU_MB;
    u16* mt = (u16*)ws + WU_MT;
    __shared__ __align__(16) u16 tile[64][72];
    const int i0 = blockIdx.x * 64;
    const int t = threadIdx.x;
    {
        const int r = t >> 2, cb = (t & 3) * 16;   // 4 threads/row x 16 u16 = 64 cols
        *(uint4*)&tile[r][cb]     = *(const uint4*)&mb[(size_t)(i0 + r) * 64 + cb];
        *(uint4*)&tile[r][cb + 8] = *(const uint4*)&mb[(size_t)(i0 + r) * 64 + cb + 8];
    }
    __syncthreads();
    const int c = t >> 2, rb = (t & 3) * 16;
    u16 tmp[16];
    #pragma unroll
    for (int i = 0; i < 16; i++) tmp[i] = tile[rb + i][c];
    *(uint4*)&mt[(size_t)c * N + i0 + rb]     = *(uint4*)&tmp[0];
    *(uint4*)&mt[(size_t)c * N + i0 + rb + 8] = *(uint4*)&tmp[8];
}

// ---------------- Kernel C: barrier-free MFMA streaming attention ----------------
// 4 independent waves per block, each owning a 16-row Q strip. No cooperative
// LDS staging: K/Mt/Q fragments are read straight from the L2-resident
// workspace; the adjacency matrix streams from HBM exactly once with a one-tile
// register prefetch. S is computed TRANSPOSED (mfma(K,Q)) so each lane holds P
// for a single q-row: adj/st become per-lane float4 loads and the softmax
// denominator is one register. P is re-laid-out for the PV A-fragment through a
// per-wave private LDS strip (same-wave ds ops => lgkmcnt only, no barriers).
__global__ __launch_bounds__(256, 4) void attn_k(const float* __restrict__ adj,
                                                 float* __restrict__ ws)
{
    const int rb = blockIdx.x, sp = blockIdx.y;
    const int i0 = rb * 64, j0 = sp * CPS;
    const int tid = threadIdx.x;
    const int w = tid >> 6, lane = tid & 63;
    const int quad = lane >> 4, n16 = lane & 15;
    const int m0 = w * 16;

    __shared__ __align__(16) u16 ps[4][16][72];     // 9.2 KB, per-wave private strips

    const u16* qb = (const u16*)ws + WU_QB;
    const u16* kb = (const u16*)ws + WU_KB;
    const u16* mt = (const u16*)ws + WU_MT;

    // Q fragment for this wave's 16 rows (B-operand of swapped S^T mfma)
    const u16* qr = qb + (size_t)(i0 + m0 + n16) * 64;
    const bf16x8 aq0 = *(const bf16x8*)&qr[quad * 8];
    const bf16x8 aq1 = *(const bf16x8*)&qr[32 + quad * 8];

    const float sbr = ws[WS_SBI + i0 + m0 + n16];   // per-lane q-row bias coef
    const float* adjrow = adj + (size_t)(i0 + m0 + n16) * N;

    f32x4 acc[4];
    #pragma unroll
    for (int i = 0; i < 4; i++) acc[i] = (f32x4){0.f, 0.f, 0.f, 0.f};
    float den = 0.0f;

    // prefetch tile 0 adj (HBM) into registers
    f32x4 a4[4];
    #pragma unroll
    for (int ct = 0; ct < 4; ct++)
        a4[ct] = *(const f32x4*)&adjrow[j0 + ct * 16 + quad * 4];

    for (int t = 0; t < NTILE; t++) {
        const int jt = j0 + t * 64;

        // issue next tile's adj loads first (HBM latency hides under this tile)
        f32x4 a4n[4];
        if (t + 1 < NTILE) {
            const int jn = jt + 64;
            #pragma unroll
            for (int ct = 0; ct < 4; ct++)
                a4n[ct] = *(const f32x4*)&adjrow[jn + ct * 16 + quad * 4];
        }

        // S^T phase: per ct, S^T[k = ct*16+quad*4+reg][q = n16]
        #pragma unroll
        for (int ct = 0; ct < 4; ct++) {
            const u16* kr = kb + (size_t)(jt + ct * 16 + n16) * 64;
            const bf16x8 k0 = *(const bf16x8*)&kr[quad * 8];
            const bf16x8 k1 = *(const bf16x8*)&kr[32 + quad * 8];
            f32x4 s = {0.f, 0.f, 0.f, 0.f};
            s = __builtin_amdgcn_mfma_f32_16x16x32_bf16(k0, aq0, s, 0, 0, 0);
            s = __builtin_amdgcn_mfma_f32_16x16x32_bf16(k1, aq1, s, 0, 0, 0);
            const f32x4 sv = *(const f32x4*)&ws[WS_ST + jt + ct * 16 + quad * 4];
            const f32x4 av = a4[ct];
            float pv[4];
            #pragma unroll
            for (int r = 0; r < 4; r++) {
                const float e = av[r] * __expf(fmaf(sbr, sv[r], s[r]));
                den += e;
                pv[r] = e;
            }
            // P^T strip: ps[w][q=n16][k]; this lane owns k = ct*16+quad*4..+3
            *(uint2*)&ps[w][n16][ct * 16 + quad * 4] =
                make_uint2(pk2(pv[0], pv[1]), pk2(pv[2], pv[3]));
        }

        // PV: read back own strip as A-fragment (row = q = n16, k = quad*8+j)
        const bf16x8 ap0 = *(const bf16x8*)&ps[w][n16][quad * 8];
        const bf16x8 ap1 = *(const bf16x8*)&ps[w][n16][32 + quad * 8];
        #pragma unroll
        for (int nt = 0; nt < 4; nt++) {
            const u16* mr = mt + (size_t)(nt * 16 + n16) * N + jt;
            const bf16x8 b0 = *(const bf16x8*)&mr[quad * 8];
            const bf16x8 b1 = *(const bf16x8*)&mr[32 + quad * 8];
            acc[nt] = __builtin_amdgcn_mfma_f32_16x16x32_bf16(ap0, b0, acc[nt], 0, 0, 0);
            acc[nt] = __builtin_amdgcn_mfma_f32_16x16x32_bf16(ap1, b1, acc[nt], 0, 0, 0);
        }

        #pragma unroll
        for (int ct = 0; ct < 4; ct++) a4[ct] = a4n[ct];
    }

    // write agg partials: lane holds D[q = quad*4+reg][h = nt*16+n16]
    float* aggp = ws + WS_AGG + (size_t)sp * N * 64;
    #pragma unroll
    for (int nt = 0; nt < 4; nt++) {
        #pragma unroll
        for (int reg = 0; reg < 4; reg++) {
            aggp[(size_t)(i0 + m0 + quad * 4 + reg) * 64 + nt * 16 + n16] = acc[nt][reg];
        }
    }
    // denominator: reduce the 4 quads holding the same q-row
    den += __shfl_xor(den, 16, 64);
    den += __shfl_xor(den, 32, 64);
    if (quad == 0) ws[WS_DEN + sp * N + i0 + m0 + n16] = den;
}

// ---------------- Kernel D: combine + LayerNorm + final MLP ----------------
__global__ __launch_bounds__(256) void final_k(
    const float* __restrict__ sa, const float* __restrict__ ln_g,
    const float* __restrict__ ln_b,
    const float* __restrict__ wa1, const float* __restrict__ ba1,
    const float* __restrict__ wa2, const float* __restrict__ ba2,
    const float* __restrict__ ws, float* __restrict__ out)
{
    const int w = threadIdx.x >> 6, lane = threadIdx.x & 63;
    const int row = blockIdx.x * 4 + w;
    __shared__ float es[4][64], hs2[4][64];
    float a = 0.0f;
    #pragma unroll
    for (int sp = 0; sp < NSPLIT; sp++)
        a += ws[WS_AGG + (size_t)sp * N * 64 + (size_t)row * 64 + lane];
    float d = 0.0f;
    #pragma unroll
    for (int sp = 0; sp < NSPLIT; sp++) d += ws[WS_DEN + sp * N + row];
    const float z = ws[WS_H + row * 64 + lane] + a / d;
    float mu = z;
    for (int off = 32; off; off >>= 1) mu += __shfl_xor(mu, off, 64);
    mu *= (1.0f / 64.0f);
    const float zc = z - mu;
    float var = zc * zc;
    for (int off = 32; off; off >>= 1) var += __shfl_xor(var, off, 64);
    var *= (1.0f / 64.0f);
    const float emb = zc * rsqrtf(var + EPSV) * ln_g[lane] + ln_b[lane];
    es[w][lane] = emb;
    __syncthreads();
    const float sa0 = sa[row * 2], sa1 = sa[row * 2 + 1];
    float hv = ba1[lane];
    #pragma unroll 8
    for (int c = 0; c < 64; c++) hv = fmaf(es[w][c], wa1[c * 64 + lane], hv);
    hv = fmaf(sa0, wa1[64 * 64 + lane], hv);
    hv = fmaf(sa1, wa1[65 * 64 + lane], hv);
    hs2[w][lane] = fmaxf(hv, 0.0f);
    __syncthreads();
    if (lane < 3) {
        float o = ba2[lane];
        for (int u = 0; u < 64; u++) o = fmaf(hs2[w][u], wa2[u * 3 + lane], o);
        out[row * 3 + lane] = o;
    }
}

extern "C" void kernel_launch(void* const* d_in, const int* in_sizes, int n_in,
                              void* d_out, int out_size, void* d_ws, size_t ws_size,
                              hipStream_t stream)
{
    const float* nf  = (const float*)d_in[0];
    const float* adj = (const float*)d_in[1];
    const float* tc  = (const float*)d_in[2];
    const float* sa  = (const float*)d_in[3];
    const float* w1  = (const float*)d_in[4];
    const float* b1  = (const float*)d_in[5];
    const float* w2  = (const float*)d_in[6];
    const float* b2  = (const float*)d_in[7];
    const float* wq  = (const float*)d_in[8];
    const float* bq  = (const float*)d_in[9];
    const float* wk  = (const float*)d_in[10];
    const float* bk  = (const float*)d_in[11];
    const float* wg  = (const float*)d_in[12];
    const float* bg  = (const float*)d_in[13];
    const float* sb  = (const float*)d_in[14];
    const float* wm  = (const float*)d_in[15];
    const float* bm  = (const float*)d_in[16];
    const float* lng = (const float*)d_in[17];
    const float* lnb = (const float*)d_in[18];
    const float* wa1 = (const float*)d_in[19];
    const float* ba1 = (const float*)d_in[20];
    const float* wa2 = (const float*)d_in[21];
    const float* ba2 = (const float*)d_in[22];
    float* ws  = (float*)d_ws;
    float* out = (float*)d_out;

    prep_k<<<1, 64, 0, stream>>>(tc, wg, bg, sb, ws + WS_SCAL);
    embed_k<<<N / 4, 256, 0, stream>>>(nf, tc, w1, b1, w2, b2, wq, bq, wk, bk,
                                       wm, bm, ws);
    transp_k<<<N / 64, 256, 0, stream>>>(ws);
    attn_k<<<dim3(N / 64, NSPLIT), 256, 0, stream>>>(adj, ws);
    final_k<<<N / 4, 256, 0, stream>>>(sa, lng, lnb, wa1, ba1, wa2, ba2, ws, out);
}

// Round 3
// 496.784 us; speedup vs baseline: 1.0916x; 1.0916x over previous
//
#include <hip/hip_runtime.h>
#include <hip/hip_bf16.h>
#include <math.h>

#define N 8192
#define NEGV -1000000000.0f
#define EPSV 1e-05f
#define NSPLIT 8
#define CPS (N / NSPLIT)   // 1024 columns per split
#define NTILE (CPS / 64)   // 16 tiles

typedef short bf16x8 __attribute__((ext_vector_type(8)));
typedef float f32x4 __attribute__((ext_vector_type(4)));
typedef unsigned short u16;
typedef unsigned int u32;

// ---- float workspace layout ----
#define WS_SCAL 0
#define WS_H    64                        // N*64 fp32
#define WS_ST   (WS_H + N * 64)           // N
#define WS_SBI  (WS_ST + N)               // N
#define WS_DEN  (WS_SBI + N)              // NSPLIT*N
#define WS_AGG  (WS_DEN + NSPLIT * N)     // NSPLIT*N*64
#define WS_F_END (WS_AGG + NSPLIT * N * 64)
// ---- u16 (bf16) region, offsets in u16 units from (u16*)ws ----
#define WU_BASE (WS_F_END * 2)
#define WU_QB (WU_BASE)                   // N*64
#define WU_KB (WU_BASE + N * 64)          // N*64
#define WU_MB (WU_BASE + 2 * N * 64)      // N*64 (row-major, transposed later)
#define WU_MT (WU_BASE + 3 * N * 64)      // 64*N

static __device__ __forceinline__ u16 f2bf(float f) {
    __hip_bfloat16 h = __float2bfloat16(f);
    return *(u16*)&h;
}
static __device__ __forceinline__ u32 pk2(float a, float b) {
    return (u32)f2bf(a) | ((u32)f2bf(b) << 16);
}

// ---------------- Kernel A: scalar prep ----------------
__global__ void prep_k(const float* __restrict__ tc, const float* __restrict__ wg,
                       const float* __restrict__ bg, const float* __restrict__ sbias,
                       float* __restrict__ scal) {
    int j = threadIdx.x;  // 64 threads
    float v = tc[0] * wg[j] + tc[1] * wg[64 + j] + bg[j];
    float g = 1.0f / (1.0f + __expf(-v));
    for (int off = 32; off; off >>= 1) g += __shfl_xor(g, off, 64);
    if (j == 0) {
        scal[0] = 0.125f * (g * (1.0f / 64.0f));   // qscale (gate mean + 1/sqrt(64) folded)
        scal[1] = sbias[0] * (1.0f - tc[0]);        // coef
    }
}

// ---------------- Kernel B: embed (h fp32; q,k,m bf16; st, sbi) ----------------
__global__ __launch_bounds__(256) void embed_k(
    const float* __restrict__ nf, const float* __restrict__ tc,
    const float* __restrict__ w1, const float* __restrict__ b1,
    const float* __restrict__ w2, const float* __restrict__ b2,
    const float* __restrict__ wq, const float* __restrict__ bq,
    const float* __restrict__ wk, const float* __restrict__ bk,
    const float* __restrict__ wm, const float* __restrict__ bm,
    float* __restrict__ ws)
{
    const int w = threadIdx.x >> 6, lane = threadIdx.x & 63;
    const int row = blockIdx.x * 4 + w;
    __shared__ float ts[4][64], hs[4][64];
    const float qscale = ws[WS_SCAL + 0];
    const float coef   = ws[WS_SCAL + 1];
    const float f0 = nf[row * 3], f1 = nf[row * 3 + 1], f2 = nf[row * 3 + 2];
    const float t0 = tc[0], t1 = tc[1];
    float v = b1[lane];
    v = fmaf(f0, w1[lane], v);
    v = fmaf(f1, w1[64 + lane], v);
    v = fmaf(f2, w1[128 + lane], v);
    v = fmaf(t0, w1[192 + lane], v);
    v = fmaf(t1, w1[256 + lane], v);
    ts[w][lane] = fmaxf(v, 0.0f);
    __syncthreads();
    float hv = b2[lane];
    #pragma unroll 8
    for (int j = 0; j < 64; j++) hv = fmaf(ts[w][j], w2[j * 64 + lane], hv);
    hs[w][lane] = hv;
    ws[WS_H + row * 64 + lane] = hv;
    __syncthreads();
    float qv = bq[lane], kv = bk[lane], mv = bm[lane];
    #pragma unroll 4
    for (int j = 0; j < 64; j++) {
        const float hj = hs[w][j];
        qv = fmaf(hj, wq[j * 64 + lane], qv);
        kv = fmaf(hj, wk[j * 64 + lane], kv);
        mv = fmaf(hj, wm[j * 64 + lane], mv);
    }
    u16* wu = (u16*)ws;
    wu[WU_QB + row * 64 + lane] = f2bf(qv * qscale);
    wu[WU_KB + row * 64 + lane] = f2bf(kv);
    wu[WU_MB + row * 64 + lane] = f2bf(mv);
    if (lane == 0) {
        ws[WS_ST + row]  = f2;
        ws[WS_SBI + row] = f2 * coef;
    }
}

// ---------------- Kernel B2: transpose M (bf16) ----------------
// NOTE: uint4 = 16 BYTES = 8 u16 elements. Each thread moves 16 u16 (two uint4).
__global__ __launch_bounds__(256) void transp_k(float* __restrict__ ws) {
    const u16* mb = (const u16*)ws + WU_MB;
    u16* mt = (u16*)ws + WU_MT;
    __shared__ __align__(16) u16 tile[64][72];
    const int i0 = blockIdx.x * 64;
    const int t = threadIdx.x;
    {
        const int r = t >> 2, cb = (t & 3) * 16;   // 4 threads/row x 16 u16 = 64 cols
        *(uint4*)&tile[r][cb]     = *(const uint4*)&mb[(size_t)(i0 + r) * 64 + cb];
        *(uint4*)&tile[r][cb + 8] = *(const uint4*)&mb[(size_t)(i0 + r) * 64 + cb + 8];
    }
    __syncthreads();
    const int c = t >> 2, rb = (t & 3) * 16;
    u16 tmp[16];
    #pragma unroll
    for (int i = 0; i < 16; i++) tmp[i] = tile[rb + i][c];
    *(uint4*)&mt[(size_t)c * N + i0 + rb]     = *(uint4*)&tmp[0];
    *(uint4*)&mt[(size_t)c * N + i0 + rb + 8] = *(uint4*)&tmp[8];
}

// ---------------- Kernel C: staged MFMA streaming attention ----------------
// 8 waves / 512 threads per block; block owns 128 q-rows and streams its
// split's columns in 64-wide tiles. K/Mt staged to double-buffered LDS
// (coalesced uint4), ONE barrier per tile: stage loads are issued at tile top
// (oldest in vmcnt queue), ds_writes deferred until after compute (T14).
// S is computed TRANSPOSED (mfma(K,Q)) so each lane holds P for one q-row:
// adj loads are per-lane float4 (HBM stream, double-buffered in registers,
// issued AFTER stage loads so K/M waits don't drain the HBM queue), softmax
// denominator is one register, P goes through a per-wave-private LDS strip.
__global__ __launch_bounds__(512, 4) void attn_k(const float* __restrict__ adj,
                                                 float* __restrict__ ws)
{
    const int rb = blockIdx.x, sp = blockIdx.y;
    const int i0 = rb * 128, j0 = sp * CPS;
    const int tid = threadIdx.x;
    const int w = tid >> 6, lane = tid & 63;
    const int quad = lane >> 4, n16 = lane & 15;
    const int m0 = w * 16;

    __shared__ __align__(16) u16 ks[2][64][72];     // 18.4 KB
    __shared__ __align__(16) u16 ms[2][64][72];     // 18.4 KB
    __shared__ __align__(16) u16 ps[8][16][72];     // 18.4 KB per-wave strips
    __shared__ float stl[CPS];                      //  4.0 KB (whole split's st)

    const u16* qb = (const u16*)ws + WU_QB;
    const u16* kb = (const u16*)ws + WU_KB;
    const u16* mt = (const u16*)ws + WU_MT;

    // staging map: 8 threads per row, each thread moves one uint4 (8 u16)
    const int sr = tid >> 3, scb = (tid & 7) * 8;

    // prologue: stage tile 0 + whole-split st
    *(uint4*)&ks[0][sr][scb] = *(const uint4*)&kb[(size_t)(j0 + sr) * 64 + scb];
    *(uint4*)&ms[0][sr][scb] = *(const uint4*)&mt[(size_t)sr * N + j0 + scb];
    stl[tid]       = ws[WS_ST + j0 + tid];
    stl[tid + 512] = ws[WS_ST + j0 + tid + 512];
    __syncthreads();

    // Q fragment for this wave's 16 rows (B-operand of swapped S^T mfma)
    const u16* qr = qb + (size_t)(i0 + m0 + n16) * 64;
    const bf16x8 aq0 = *(const bf16x8*)&qr[quad * 8];
    const bf16x8 aq1 = *(const bf16x8*)&qr[32 + quad * 8];

    const float sbr = ws[WS_SBI + i0 + m0 + n16];   // per-lane q-row bias coef
    const float* adjrow = adj + (size_t)(i0 + m0 + n16) * N;

    f32x4 acc[4];
    #pragma unroll
    for (int i = 0; i < 4; i++) acc[i] = (f32x4){0.f, 0.f, 0.f, 0.f};
    float den = 0.0f;

    // prefetch tile 0 adj (HBM) into registers
    f32x4 a4[4];
    #pragma unroll
    for (int ct = 0; ct < 4; ct++)
        a4[ct] = *(const f32x4*)&adjrow[j0 + ct * 16 + quad * 4];

    for (int t = 0; t < NTILE; t++) {
        const int cur = t & 1;
        const int jt = j0 + t * 64;
        const bool hn = (t + 1 < NTILE);
        const int jn = jt + 64;

        // issue next tile's stage loads FIRST (oldest in vmcnt queue: waiting
        // on them at the deferred ds_write does not wait on the adj stream)
        uint4 rk, rm;
        if (hn) {
            rk = *(const uint4*)&kb[(size_t)(jn + sr) * 64 + scb];
            rm = *(const uint4*)&mt[(size_t)sr * N + jn + scb];
        }
        // then next tile's adj (HBM latency hides under this tile's compute)
        f32x4 a4n[4];
        if (hn) {
            #pragma unroll
            for (int ct = 0; ct < 4; ct++)
                a4n[ct] = *(const f32x4*)&adjrow[jn + ct * 16 + quad * 4];
        }

        // S^T phase: per ct, S^T[k = ct*16+quad*4+reg][q = n16]
        #pragma unroll
        for (int ct = 0; ct < 4; ct++) {
            const bf16x8 k0 = *(const bf16x8*)&ks[cur][ct * 16 + n16][quad * 8];
            const bf16x8 k1 = *(const bf16x8*)&ks[cur][ct * 16 + n16][32 + quad * 8];
            f32x4 s = {0.f, 0.f, 0.f, 0.f};
            s = __builtin_amdgcn_mfma_f32_16x16x32_bf16(k0, aq0, s, 0, 0, 0);
            s = __builtin_amdgcn_mfma_f32_16x16x32_bf16(k1, aq1, s, 0, 0, 0);
            const f32x4 sv = *(const f32x4*)&stl[t * 64 + ct * 16 + quad * 4];
            const f32x4 av = a4[ct];
            float pv[4];
            #pragma unroll
            for (int r = 0; r < 4; r++) {
                const float e = av[r] * __expf(fmaf(sbr, sv[r], s[r]));
                den += e;
                pv[r] = e;
            }
            // P^T strip: ps[w][q=n16][k]; this lane owns k = ct*16+quad*4..+3
            *(uint2*)&ps[w][n16][ct * 16 + quad * 4] =
                make_uint2(pk2(pv[0], pv[1]), pk2(pv[2], pv[3]));
        }

        // PV: read back own strip as A-fragment (row = q = n16, k = quad*8+j)
        const bf16x8 ap0 = *(const bf16x8*)&ps[w][n16][quad * 8];
        const bf16x8 ap1 = *(const bf16x8*)&ps[w][n16][32 + quad * 8];
        #pragma unroll
        for (int nt = 0; nt < 4; nt++) {
            const bf16x8 b0 = *(const bf16x8*)&ms[cur][nt * 16 + n16][quad * 8];
            const bf16x8 b1 = *(const bf16x8*)&ms[cur][nt * 16 + n16][32 + quad * 8];
            acc[nt] = __builtin_amdgcn_mfma_f32_16x16x32_bf16(ap0, b0, acc[nt], 0, 0, 0);
            acc[nt] = __builtin_amdgcn_mfma_f32_16x16x32_bf16(ap1, b1, acc[nt], 0, 0, 0);
        }

        // deferred stage writes (T14 write-late), then the tile's ONE barrier
        if (hn) {
            *(uint4*)&ks[cur ^ 1][sr][scb] = rk;
            *(uint4*)&ms[cur ^ 1][sr][scb] = rm;
        }
        __syncthreads();

        #pragma unroll
        for (int ct = 0; ct < 4; ct++) a4[ct] = a4n[ct];
    }

    // write agg partials: lane holds D[q = quad*4+reg][h = nt*16+n16]
    float* aggp = ws + WS_AGG + (size_t)sp * N * 64;
    #pragma unroll
    for (int nt = 0; nt < 4; nt++) {
        #pragma unroll
        for (int reg = 0; reg < 4; reg++) {
            aggp[(size_t)(i0 + m0 + quad * 4 + reg) * 64 + nt * 16 + n16] = acc[nt][reg];
        }
    }
    // denominator: reduce the 4 quads holding the same q-row
    den += __shfl_xor(den, 16, 64);
    den += __shfl_xor(den, 32, 64);
    if (quad == 0) ws[WS_DEN + sp * N + i0 + m0 + n16] = den;
}

// ---------------- Kernel D: combine + LayerNorm + final MLP ----------------
__global__ __launch_bounds__(256) void final_k(
    const float* __restrict__ sa, const float* __restrict__ ln_g,
    const float* __restrict__ ln_b,
    const float* __restrict__ wa1, const float* __restrict__ ba1,
    const float* __restrict__ wa2, const float* __restrict__ ba2,
    const float* __restrict__ ws, float* __restrict__ out)
{
    const int w = threadIdx.x >> 6, lane = threadIdx.x & 63;
    const int row = blockIdx.x * 4 + w;
    __shared__ float es[4][64], hs2[4][64];
    float a = 0.0f;
    #pragma unroll
    for (int sp = 0; sp < NSPLIT; sp++)
        a += ws[WS_AGG + (size_t)sp * N * 64 + (size_t)row * 64 + lane];
    float d = 0.0f;
    #pragma unroll
    for (int sp = 0; sp < NSPLIT; sp++) d += ws[WS_DEN + sp * N + row];
    const float z = ws[WS_H + row * 64 + lane] + a / d;
    float mu = z;
    for (int off = 32; off; off >>= 1) mu += __shfl_xor(mu, off, 64);
    mu *= (1.0f / 64.0f);
    const float zc = z - mu;
    float var = zc * zc;
    for (int off = 32; off; off >>= 1) var += __shfl_xor(var, off, 64);
    var *= (1.0f / 64.0f);
    const float emb = zc * rsqrtf(var + EPSV) * ln_g[lane] + ln_b[lane];
    es[w][lane] = emb;
    __syncthreads();
    const float sa0 = sa[row * 2], sa1 = sa[row * 2 + 1];
    float hv = ba1[lane];
    #pragma unroll 8
    for (int c = 0; c < 64; c++) hv = fmaf(es[w][c], wa1[c * 64 + lane], hv);
    hv = fmaf(sa0, wa1[64 * 64 + lane], hv);
    hv = fmaf(sa1, wa1[65 * 64 + lane], hv);
    hs2[w][lane] = fmaxf(hv, 0.0f);
    __syncthreads();
    if (lane < 3) {
        float o = ba2[lane];
        for (int u = 0; u < 64; u++) o = fmaf(hs2[w][u], wa2[u * 3 + lane], o);
        out[row * 3 + lane] = o;
    }
}

extern "C" void kernel_launch(void* const* d_in, const int* in_sizes, int n_in,
                              void* d_out, int out_size, void* d_ws, size_t ws_size,
                              hipStream_t stream)
{
    const float* nf  = (const float*)d_in[0];
    const float* adj = (const float*)d_in[1];
    const float* tc  = (const float*)d_in[2];
    const float* sa  = (const float*)d_in[3];
    const float* w1  = (const float*)d_in[4];
    const float* b1  = (const float*)d_in[5];
    const float* w2  = (const float*)d_in[6];
    const float* b2  = (const float*)d_in[7];
    const float* wq  = (const float*)d_in[8];
    const float* bq  = (const float*)d_in[9];
    const float* wk  = (const float*)d_in[10];
    const float* bk  = (const float*)d_in[11];
    const float* wg  = (const float*)d_in[12];
    const float* bg  = (const float*)d_in[13];
    const float* sb  = (const float*)d_in[14];
    const float* wm  = (const float*)d_in[15];
    const float* bm  = (const float*)d_in[16];
    const float* lng = (const float*)d_in[17];
    const float* lnb = (const float*)d_in[18];
    const float* wa1 = (const float*)d_in[19];
    const float* ba1 = (const float*)d_in[20];
    const float* wa2 = (const float*)d_in[21];
    const float* ba2 = (const float*)d_in[22];
    float* ws  = (float*)d_ws;
    float* out = (float*)d_out;

    prep_k<<<1, 64, 0, stream>>>(tc, wg, bg, sb, ws + WS_SCAL);
    embed_k<<<N / 4, 256, 0, stream>>>(nf, tc, w1, b1, w2, b2, wq, bq, wk, bk,
                                       wm, bm, ws);
    transp_k<<<N / 64, 256, 0, stream>>>(ws);
    attn_k<<<dim3(N / 128, NSPLIT), 512, 0, stream>>>(adj, ws);
    final_k<<<N / 4, 256, 0, stream>>>(sa, lng, lnb, wa1, ba1, wa2, ba2, ws, out);
}

// Round 4
// 483.607 us; speedup vs baseline: 1.1213x; 1.0272x over previous
//
#include <hip/hip_runtime.h>
#include <hip/hip_bf16.h>
#include <math.h>

#define N 8192
#define NEGV -1000000000.0f
#define EPSV 1e-05f
#define NSPLIT 8
#define CPS (N / NSPLIT)   // 1024 columns per split
#define NTILE (CPS / 64)   // 16 tiles

typedef short bf16x8 __attribute__((ext_vector_type(8)));
typedef float f32x4 __attribute__((ext_vector_type(4)));
typedef unsigned short u16;
typedef unsigned int u32;

// ---- float workspace layout ----
#define WS_SCAL 0
#define WS_H    64                        // N*64 fp32
#define WS_ST   (WS_H + N * 64)           // N
#define WS_SBI  (WS_ST + N)               // N
#define WS_DEN  (WS_SBI + N)              // NSPLIT*N
#define WS_AGG  (WS_DEN + NSPLIT * N)     // NSPLIT*N*64
#define WS_F_END (WS_AGG + NSPLIT * N * 64)
// ---- u16 (bf16) region, offsets in u16 units from (u16*)ws ----
#define WU_BASE (WS_F_END * 2)
#define WU_QB (WU_BASE)                   // N*64
#define WU_KB (WU_BASE + N * 64)          // N*64
#define WU_MB (WU_BASE + 2 * N * 64)      // N*64 (row-major, transposed later)
#define WU_MT (WU_BASE + 3 * N * 64)      // 64*N

static __device__ __forceinline__ u16 f2bf(float f) {
    __hip_bfloat16 h = __float2bfloat16(f);
    return *(u16*)&h;
}
static __device__ __forceinline__ u32 pk2(float a, float b) {
    return (u32)f2bf(a) | ((u32)f2bf(b) << 16);
}

// Counted barrier (T4): order LDS (lgkmcnt) but do NOT drain vmcnt, so
// global prefetch loads issued this tile stay in flight across the barrier.
// Safe here because the only cross-wave hazard is LDS (double-buffered K/Mt):
// lgkmcnt(0)+s_barrier makes all ds_writes visible; no global_load_lds and no
// cross-wave global writes exist in the loop. "memory" clobber pins ordering.
#define TILE_BARRIER() asm volatile("s_waitcnt lgkmcnt(0)\n\ts_barrier" ::: "memory")

// ---------------- Kernel A: scalar prep ----------------
__global__ void prep_k(const float* __restrict__ tc, const float* __restrict__ wg,
                       const float* __restrict__ bg, const float* __restrict__ sbias,
                       float* __restrict__ scal) {
    int j = threadIdx.x;  // 64 threads
    float v = tc[0] * wg[j] + tc[1] * wg[64 + j] + bg[j];
    float g = 1.0f / (1.0f + __expf(-v));
    for (int off = 32; off; off >>= 1) g += __shfl_xor(g, off, 64);
    if (j == 0) {
        scal[0] = 0.125f * (g * (1.0f / 64.0f));   // qscale (gate mean + 1/sqrt(64) folded)
        scal[1] = sbias[0] * (1.0f - tc[0]);        // coef
    }
}

// ---------------- Kernel B: embed (h fp32; q,k,m bf16; st, sbi) ----------------
__global__ __launch_bounds__(256) void embed_k(
    const float* __restrict__ nf, const float* __restrict__ tc,
    const float* __restrict__ w1, const float* __restrict__ b1,
    const float* __restrict__ w2, const float* __restrict__ b2,
    const float* __restrict__ wq, const float* __restrict__ bq,
    const float* __restrict__ wk, const float* __restrict__ bk,
    const float* __restrict__ wm, const float* __restrict__ bm,
    float* __restrict__ ws)
{
    const int w = threadIdx.x >> 6, lane = threadIdx.x & 63;
    const int row = blockIdx.x * 4 + w;
    __shared__ float ts[4][64], hs[4][64];
    const float qscale = ws[WS_SCAL + 0];
    const float coef   = ws[WS_SCAL + 1];
    const float f0 = nf[row * 3], f1 = nf[row * 3 + 1], f2 = nf[row * 3 + 2];
    const float t0 = tc[0], t1 = tc[1];
    float v = b1[lane];
    v = fmaf(f0, w1[lane], v);
    v = fmaf(f1, w1[64 + lane], v);
    v = fmaf(f2, w1[128 + lane], v);
    v = fmaf(t0, w1[192 + lane], v);
    v = fmaf(t1, w1[256 + lane], v);
    ts[w][lane] = fmaxf(v, 0.0f);
    __syncthreads();
    float hv = b2[lane];
    #pragma unroll 8
    for (int j = 0; j < 64; j++) hv = fmaf(ts[w][j], w2[j * 64 + lane], hv);
    hs[w][lane] = hv;
    ws[WS_H + row * 64 + lane] = hv;
    __syncthreads();
    float qv = bq[lane], kv = bk[lane], mv = bm[lane];
    #pragma unroll 4
    for (int j = 0; j < 64; j++) {
        const float hj = hs[w][j];
        qv = fmaf(hj, wq[j * 64 + lane], qv);
        kv = fmaf(hj, wk[j * 64 + lane], kv);
        mv = fmaf(hj, wm[j * 64 + lane], mv);
    }
    u16* wu = (u16*)ws;
    wu[WU_QB + row * 64 + lane] = f2bf(qv * qscale);
    wu[WU_KB + row * 64 + lane] = f2bf(kv);
    wu[WU_MB + row * 64 + lane] = f2bf(mv);
    if (lane == 0) {
        ws[WS_ST + row]  = f2;
        ws[WS_SBI + row] = f2 * coef;
    }
}

// ---------------- Kernel B2: transpose M (bf16) ----------------
// NOTE: uint4 = 16 BYTES = 8 u16 elements. Each thread moves 16 u16 (two uint4).
__global__ __launch_bounds__(256) void transp_k(float* __restrict__ ws) {
    const u16* mb = (const u16*)ws + WU_MB;
    u16* mt = (u16*)ws + WU_MT;
    __shared__ __align__(16) u16 tile[64][72];
    const int i0 = blockIdx.x * 64;
    const int t = threadIdx.x;
    {
        const int r = t >> 2, cb = (t & 3) * 16;   // 4 threads/row x 16 u16 = 64 cols
        *(uint4*)&tile[r][cb]     = *(const uint4*)&mb[(size_t)(i0 + r) * 64 + cb];
        *(uint4*)&tile[r][cb + 8] = *(const uint4*)&mb[(size_t)(i0 + r) * 64 + cb + 8];
    }
    __syncthreads();
    const int c = t >> 2, rb = (t & 3) * 16;
    u16 tmp[16];
    #pragma unroll
    for (int i = 0; i < 16; i++) tmp[i] = tile[rb + i][c];
    *(uint4*)&mt[(size_t)c * N + i0 + rb]     = *(uint4*)&tmp[0];
    *(uint4*)&mt[(size_t)c * N + i0 + rb + 8] = *(uint4*)&tmp[8];
}

// ---------------- Kernel C: staged MFMA streaming attention ----------------
// 8 waves / 512 threads per block; block owns 128 q-rows and streams its
// split's columns in 64-wide tiles. K/Mt staged to double-buffered LDS
// (coalesced uint4), ONE counted barrier per tile: stage loads issued at tile
// top (oldest in vmcnt queue -> deferred ds_write waits vmcnt(4), keeping the
// 4 adj loads in flight), ds_writes deferred until after compute (T14), and
// the barrier is lgkmcnt-only so the adj prefetch genuinely crosses it (T4).
// S is computed TRANSPOSED (mfma(K,Q)) so each lane holds P for one q-row.
__global__ __launch_bounds__(512, 4) void attn_k(const float* __restrict__ adj,
                                                 float* __restrict__ ws)
{
    const int rb = blockIdx.x, sp = blockIdx.y;
    const int i0 = rb * 128, j0 = sp * CPS;
    const int tid = threadIdx.x;
    const int w = tid >> 6, lane = tid & 63;
    const int quad = lane >> 4, n16 = lane & 15;
    const int m0 = w * 16;

    __shared__ __align__(16) u16 ks[2][64][72];     // 18.4 KB
    __shared__ __align__(16) u16 ms[2][64][72];     // 18.4 KB
    __shared__ __align__(16) u16 ps[8][16][72];     // 18.4 KB per-wave strips
    __shared__ float stl[CPS];                      //  4.0 KB (whole split's st)

    const u16* qb = (const u16*)ws + WU_QB;
    const u16* kb = (const u16*)ws + WU_KB;
    const u16* mt = (const u16*)ws + WU_MT;

    // staging map: 8 threads per row, each thread moves one uint4 (8 u16)
    const int sr = tid >> 3, scb = (tid & 7) * 8;

    // prologue: stage tile 0 + whole-split st (one-time full sync is fine)
    *(uint4*)&ks[0][sr][scb] = *(const uint4*)&kb[(size_t)(j0 + sr) * 64 + scb];
    *(uint4*)&ms[0][sr][scb] = *(const uint4*)&mt[(size_t)sr * N + j0 + scb];
    stl[tid]       = ws[WS_ST + j0 + tid];
    stl[tid + 512] = ws[WS_ST + j0 + tid + 512];
    __syncthreads();

    // Q fragment for this wave's 16 rows (B-operand of swapped S^T mfma)
    const u16* qr = qb + (size_t)(i0 + m0 + n16) * 64;
    const bf16x8 aq0 = *(const bf16x8*)&qr[quad * 8];
    const bf16x8 aq1 = *(const bf16x8*)&qr[32 + quad * 8];

    const float sbr = ws[WS_SBI + i0 + m0 + n16];   // per-lane q-row bias coef
    const float* adjrow = adj + (size_t)(i0 + m0 + n16) * N;

    f32x4 acc[4];
    #pragma unroll
    for (int i = 0; i < 4; i++) acc[i] = (f32x4){0.f, 0.f, 0.f, 0.f};
    float den = 0.0f;

    // prefetch tile 0 adj (HBM) into registers
    f32x4 a4[4];
    #pragma unroll
    for (int ct = 0; ct < 4; ct++)
        a4[ct] = *(const f32x4*)&adjrow[j0 + ct * 16 + quad * 4];

    for (int t = 0; t < NTILE; t++) {
        const int cur = t & 1;
        const int jt = j0 + t * 64;
        const bool hn = (t + 1 < NTILE);
        const int jn = jt + 64;

        // issue next tile's stage loads FIRST (oldest in vmcnt queue: waiting
        // on them at the deferred ds_write leaves the adj loads outstanding)
        uint4 rk, rm;
        if (hn) {
            rk = *(const uint4*)&kb[(size_t)(jn + sr) * 64 + scb];
            rm = *(const uint4*)&mt[(size_t)sr * N + jn + scb];
        }
        // then next tile's adj (stays in flight across the counted barrier)
        f32x4 a4n[4];
        if (hn) {
            #pragma unroll
            for (int ct = 0; ct < 4; ct++)
                a4n[ct] = *(const f32x4*)&adjrow[jn + ct * 16 + quad * 4];
        }

        // S^T phase: per ct, S^T[k = ct*16+quad*4+reg][q = n16]
        #pragma unroll
        for (int ct = 0; ct < 4; ct++) {
            const bf16x8 k0 = *(const bf16x8*)&ks[cur][ct * 16 + n16][quad * 8];
            const bf16x8 k1 = *(const bf16x8*)&ks[cur][ct * 16 + n16][32 + quad * 8];
            f32x4 s = {0.f, 0.f, 0.f, 0.f};
            s = __builtin_amdgcn_mfma_f32_16x16x32_bf16(k0, aq0, s, 0, 0, 0);
            s = __builtin_amdgcn_mfma_f32_16x16x32_bf16(k1, aq1, s, 0, 0, 0);
            const f32x4 sv = *(const f32x4*)&stl[t * 64 + ct * 16 + quad * 4];
            const f32x4 av = a4[ct];
            float pv[4];
            #pragma unroll
            for (int r = 0; r < 4; r++) {
                const float e = av[r] * __expf(fmaf(sbr, sv[r], s[r]));
                den += e;
                pv[r] = e;
            }
            // P^T strip: ps[w][q=n16][k]; this lane owns k = ct*16+quad*4..+3
            *(uint2*)&ps[w][n16][ct * 16 + quad * 4] =
                make_uint2(pk2(pv[0], pv[1]), pk2(pv[2], pv[3]));
        }

        // PV: read back own strip as A-fragment (row = q = n16, k = quad*8+j)
        const bf16x8 ap0 = *(const bf16x8*)&ps[w][n16][quad * 8];
        const bf16x8 ap1 = *(const bf16x8*)&ps[w][n16][32 + quad * 8];
        #pragma unroll
        for (int nt = 0; nt < 4; nt++) {
            const bf16x8 b0 = *(const bf16x8*)&ms[cur][nt * 16 + n16][quad * 8];
            const bf16x8 b1 = *(const bf16x8*)&ms[cur][nt * 16 + n16][32 + quad * 8];
            acc[nt] = __builtin_amdgcn_mfma_f32_16x16x32_bf16(ap0, b0, acc[nt], 0, 0, 0);
            acc[nt] = __builtin_amdgcn_mfma_f32_16x16x32_bf16(ap1, b1, acc[nt], 0, 0, 0);
        }

        // deferred stage writes (T14 write-late): compiler waits vmcnt(4) for
        // rk/rm here (adj loads remain outstanding), then the counted barrier.
        if (hn) {
            *(uint4*)&ks[cur ^ 1][sr][scb] = rk;
            *(uint4*)&ms[cur ^ 1][sr][scb] = rm;
        }
        TILE_BARRIER();

        #pragma unroll
        for (int ct = 0; ct < 4; ct++) a4[ct] = a4n[ct];
    }

    // write agg partials: lane holds D[q = quad*4+reg][h = nt*16+n16]
    float* aggp = ws + WS_AGG + (size_t)sp * N * 64;
    #pragma unroll
    for (int nt = 0; nt < 4; nt++) {
        #pragma unroll
        for (int reg = 0; reg < 4; reg++) {
            aggp[(size_t)(i0 + m0 + quad * 4 + reg) * 64 + nt * 16 + n16] = acc[nt][reg];
        }
    }
    // denominator: reduce the 4 quads holding the same q-row
    den += __shfl_xor(den, 16, 64);
    den += __shfl_xor(den, 32, 64);
    if (quad == 0) ws[WS_DEN + sp * N + i0 + m0 + n16] = den;
}

// ---------------- Kernel D: combine + LayerNorm + final MLP ----------------
__global__ __launch_bounds__(256) void final_k(
    const float* __restrict__ sa, const float* __restrict__ ln_g,
    const float* __restrict__ ln_b,
    const float* __restrict__ wa1, const float* __restrict__ ba1,
    const float* __restrict__ wa2, const float* __restrict__ ba2,
    const float* __restrict__ ws, float* __restrict__ out)
{
    const int w = threadIdx.x >> 6, lane = threadIdx.x & 63;
    const int row = blockIdx.x * 4 + w;
    __shared__ float es[4][64], hs2[4][64];
    float a = 0.0f;
    #pragma unroll
    for (int sp = 0; sp < NSPLIT; sp++)
        a += ws[WS_AGG + (size_t)sp * N * 64 + (size_t)row * 64 + lane];
    float d = 0.0f;
    #pragma unroll
    for (int sp = 0; sp < NSPLIT; sp++) d += ws[WS_DEN + sp * N + row];
    const float z = ws[WS_H + row * 64 + lane] + a / d;
    float mu = z;
    for (int off = 32; off; off >>= 1) mu += __shfl_xor(mu, off, 64);
    mu *= (1.0f / 64.0f);
    const float zc = z - mu;
    float var = zc * zc;
    for (int off = 32; off; off >>= 1) var += __shfl_xor(var, off, 64);
    var *= (1.0f / 64.0f);
    const float emb = zc * rsqrtf(var + EPSV) * ln_g[lane] + ln_b[lane];
    es[w][lane] = emb;
    __syncthreads();
    const float sa0 = sa[row * 2], sa1 = sa[row * 2 + 1];
    float hv = ba1[lane];
    #pragma unroll 8
    for (int c = 0; c < 64; c++) hv = fmaf(es[w][c], wa1[c * 64 + lane], hv);
    hv = fmaf(sa0, wa1[64 * 64 + lane], hv);
    hv = fmaf(sa1, wa1[65 * 64 + lane], hv);
    hs2[w][lane] = fmaxf(hv, 0.0f);
    __syncthreads();
    if (lane < 3) {
        float o = ba2[lane];
        for (int u = 0; u < 64; u++) o = fmaf(hs2[w][u], wa2[u * 3 + lane], o);
        out[row * 3 + lane] = o;
    }
}

extern "C" void kernel_launch(void* const* d_in, const int* in_sizes, int n_in,
                              void* d_out, int out_size, void* d_ws, size_t ws_size,
                              hipStream_t stream)
{
    const float* nf  = (const float*)d_in[0];
    const float* adj = (const float*)d_in[1];
    const float* tc  = (const float*)d_in[2];
    const float* sa  = (const float*)d_in[3];
    const float* w1  = (const float*)d_in[4];
    const float* b1  = (const float*)d_in[5];
    const float* w2  = (const float*)d_in[6];
    const float* b2  = (const float*)d_in[7];
    const float* wq  = (const float*)d_in[8];
    const float* bq  = (const float*)d_in[9];
    const float* wk  = (const float*)d_in[10];
    const float* bk  = (const float*)d_in[11];
    const float* wg  = (const float*)d_in[12];
    const float* bg  = (const float*)d_in[13];
    const float* sb  = (const float*)d_in[14];
    const float* wm  = (const float*)d_in[15];
    const float* bm  = (const float*)d_in[16];
    const float* lng = (const float*)d_in[17];
    const float* lnb = (const float*)d_in[18];
    const float* wa1 = (const float*)d_in[19];
    const float* ba1 = (const float*)d_in[20];
    const float* wa2 = (const float*)d_in[21];
    const float* ba2 = (const float*)d_in[22];
    float* ws  = (float*)d_ws;
    float* out = (float*)d_out;

    prep_k<<<1, 64, 0, stream>>>(tc, wg, bg, sb, ws + WS_SCAL);
    embed_k<<<N / 4, 256, 0, stream>>>(nf, tc, w1, b1, w2, b2, wq, bq, wk, bk,
                                       wm, bm, ws);
    transp_k<<<N / 64, 256, 0, stream>>>(ws);
    attn_k<<<dim3(N / 128, NSPLIT), 512, 0, stream>>>(adj, ws);
    final_k<<<N / 4, 256, 0, stream>>>(sa, lng, lnb, wa1, ba1, wa2, ba2, ws, out);
}

// Round 5
// 467.126 us; speedup vs baseline: 1.1609x; 1.0353x over previous
//
#include <hip/hip_runtime.h>
#include <hip/hip_bf16.h>
#include <math.h>

#define N 8192
#define EPSV 1e-05f
#define NSPLIT 16
#define CPS (N / NSPLIT)   // 512 columns per split
#define NTILE (CPS / 64)   // 8 tiles of 64 cols

typedef short bf16x8 __attribute__((ext_vector_type(8)));
typedef float f32x4 __attribute__((ext_vector_type(4)));
typedef float f32x16 __attribute__((ext_vector_type(16)));
typedef unsigned short u16;
typedef unsigned int u32;

// ---- float workspace layout ----
#define WS_SCAL 0
#define WS_H    64                        // N*64 fp32
#define WS_ST   (WS_H + N * 64)           // N
#define WS_SBI  (WS_ST + N)               // N
#define WS_DEN  (WS_SBI + N)              // NSPLIT*N
#define WS_AGG  (WS_DEN + NSPLIT * N)     // NSPLIT*N*64
#define WS_F_END (WS_AGG + NSPLIT * N * 64)
// ---- u16 (bf16) region, offsets in u16 units from (u16*)ws ----
#define WU_BASE (WS_F_END * 2)
#define WU_QB (WU_BASE)                   // N*64
#define WU_KB (WU_BASE + N * 64)          // N*64
#define WU_MB (WU_BASE + 2 * N * 64)      // N*64 (row-major, transposed later)
#define WU_MT (WU_BASE + 3 * N * 64)      // 64*N

static __device__ __forceinline__ u16 f2bf(float f) {
    __hip_bfloat16 h = __float2bfloat16(f);
    return *(u16*)&h;
}
static __device__ __forceinline__ u32 pk2(float a, float b) {
    return (u32)f2bf(a) | ((u32)f2bf(b) << 16);
}
static __device__ __forceinline__ bf16x8 mk8(u32 a, u32 b, u32 c, u32 d) {
    union { u32 u[4]; bf16x8 v; } x;
    x.u[0] = a; x.u[1] = b; x.u[2] = c; x.u[3] = d;
    return x.v;
}

// Counted barrier (T4): order LDS (lgkmcnt) but do NOT drain vmcnt, so global
// prefetch loads stay in flight across the barrier. Only cross-wave hazard is
// the double-buffered LDS; lgkmcnt(0)+s_barrier makes all ds_writes visible.
#define TILE_BARRIER() asm volatile("s_waitcnt lgkmcnt(0)\n\ts_barrier" ::: "memory")

// ---------------- Kernel A: scalar prep ----------------
__global__ void prep_k(const float* __restrict__ tc, const float* __restrict__ wg,
                       const float* __restrict__ bg, const float* __restrict__ sbias,
                       float* __restrict__ scal) {
    int j = threadIdx.x;  // 64 threads
    float v = tc[0] * wg[j] + tc[1] * wg[64 + j] + bg[j];
    float g = 1.0f / (1.0f + __expf(-v));
    for (int off = 32; off; off >>= 1) g += __shfl_xor(g, off, 64);
    if (j == 0) {
        scal[0] = 0.125f * (g * (1.0f / 64.0f));   // qscale (gate mean + 1/sqrt(64) folded)
        scal[1] = sbias[0] * (1.0f - tc[0]);        // coef
    }
}

// ---------------- Kernel B: embed (h fp32; q,k,m bf16; st, sbi) ----------------
__global__ __launch_bounds__(256) void embed_k(
    const float* __restrict__ nf, const float* __restrict__ tc,
    const float* __restrict__ w1, const float* __restrict__ b1,
    const float* __restrict__ w2, const float* __restrict__ b2,
    const float* __restrict__ wq, const float* __restrict__ bq,
    const float* __restrict__ wk, const float* __restrict__ bk,
    const float* __restrict__ wm, const float* __restrict__ bm,
    float* __restrict__ ws)
{
    const int w = threadIdx.x >> 6, lane = threadIdx.x & 63;
    const int row = blockIdx.x * 4 + w;
    __shared__ float ts[4][64], hs[4][64];
    const float qscale = ws[WS_SCAL + 0];
    const float coef   = ws[WS_SCAL + 1];
    const float f0 = nf[row * 3], f1 = nf[row * 3 + 1], f2 = nf[row * 3 + 2];
    const float t0 = tc[0], t1 = tc[1];
    float v = b1[lane];
    v = fmaf(f0, w1[lane], v);
    v = fmaf(f1, w1[64 + lane], v);
    v = fmaf(f2, w1[128 + lane], v);
    v = fmaf(t0, w1[192 + lane], v);
    v = fmaf(t1, w1[256 + lane], v);
    ts[w][lane] = fmaxf(v, 0.0f);
    __syncthreads();
    float hv = b2[lane];
    #pragma unroll 8
    for (int j = 0; j < 64; j++) hv = fmaf(ts[w][j], w2[j * 64 + lane], hv);
    hs[w][lane] = hv;
    ws[WS_H + row * 64 + lane] = hv;
    __syncthreads();
    float qv = bq[lane], kv = bk[lane], mv = bm[lane];
    #pragma unroll 4
    for (int j = 0; j < 64; j++) {
        const float hj = hs[w][j];
        qv = fmaf(hj, wq[j * 64 + lane], qv);
        kv = fmaf(hj, wk[j * 64 + lane], kv);
        mv = fmaf(hj, wm[j * 64 + lane], mv);
    }
    u16* wu = (u16*)ws;
    wu[WU_QB + row * 64 + lane] = f2bf(qv * qscale);
    wu[WU_KB + row * 64 + lane] = f2bf(kv);
    wu[WU_MB + row * 64 + lane] = f2bf(mv);
    if (lane == 0) {
        ws[WS_ST + row]  = f2;
        ws[WS_SBI + row] = f2 * coef;
    }
}

// ---------------- Kernel B2: transpose M (bf16) ----------------
__global__ __launch_bounds__(256) void transp_k(float* __restrict__ ws) {
    const u16* mb = (const u16*)ws + WU_MB;
    u16* mt = (u16*)ws + WU_MT;
    __shared__ __align__(16) u16 tile[64][72];
    const int i0 = blockIdx.x * 64;
    const int t = threadIdx.x;
    {
        const int r = t >> 2, cb = (t & 3) * 16;
        *(uint4*)&tile[r][cb]     = *(const uint4*)&mb[(size_t)(i0 + r) * 64 + cb];
        *(uint4*)&tile[r][cb + 8] = *(const uint4*)&mb[(size_t)(i0 + r) * 64 + cb + 8];
    }
    __syncthreads();
    const int c = t >> 2, rb = (t & 3) * 16;
    u16 tmp[16];
    #pragma unroll
    for (int i = 0; i < 16; i++) tmp[i] = tile[rb + i][c];
    *(uint4*)&mt[(size_t)c * N + i0 + rb]     = *(uint4*)&tmp[0];
    *(uint4*)&mt[(size_t)c * N + i0 + rb + 8] = *(uint4*)&tmp[8];
}

// ---------------- Kernel C: 32x32 MFMA attention, shfl P-turnaround ----------------
// 4 waves / 256 threads; wave owns 32 q-rows (block: 128). Per 64-col tile,
// two 32-col k-steps. S^T = mfma32(K, Q) so lane's col is one q-row: adj/st are
// per-lane f32x4, den is a register. P is converted to the PV A-fragment with
// 8 __shfl_xor(.,32) + cndmask (no LDS strip, no write->read hop). K/Mt double-
// buffered in LDS (36.9 KB => 4 blocks/CU = 4 independent convoys), staged
// issue-early/write-late, one lgkm-only counted barrier per tile.
__global__ __launch_bounds__(256, 4) void attn_k(const float* __restrict__ adj,
                                                 float* __restrict__ ws)
{
    const int rb = blockIdx.x, sp = blockIdx.y;
    const int i0 = rb * 128, j0 = sp * CPS;
    const int tid = threadIdx.x;
    const int w = tid >> 6, lane = tid & 63;
    const int hi = lane >> 5, l31 = lane & 31;

    __shared__ __align__(16) u16 ks[2][64][68];   // 17408 B
    __shared__ __align__(16) u16 ms[2][64][68];   // 17408 B
    __shared__ float stl[CPS];                    //  2048 B

    const u16* qb  = (const u16*)ws + WU_QB;
    const u16* kbp = (const u16*)ws + WU_KB;
    const u16* mtp = (const u16*)ws + WU_MT;

    // staging map: 4 threads per row, each thread moves 2 uint4 (32 B)
    const int sr = tid >> 2, scb = (tid & 3) * 16;

    // prologue: stage tile 0 + split's st
    *(uint4*)&ks[0][sr][scb]     = *(const uint4*)&kbp[(size_t)(j0 + sr) * 64 + scb];
    *(uint4*)&ks[0][sr][scb + 8] = *(const uint4*)&kbp[(size_t)(j0 + sr) * 64 + scb + 8];
    *(uint4*)&ms[0][sr][scb]     = *(const uint4*)&mtp[(size_t)sr * N + j0 + scb];
    *(uint4*)&ms[0][sr][scb + 8] = *(const uint4*)&mtp[(size_t)sr * N + j0 + scb + 8];
    stl[tid]       = ws[WS_ST + j0 + tid];
    stl[tid + 256] = ws[WS_ST + j0 + tid + 256];
    __syncthreads();

    // Q fragments: lane's q-row is l31 of the wave's 32-row strip
    const int qrow = i0 + w * 32 + l31;
    const u16* qr = qb + (size_t)qrow * 64;
    bf16x8 qf[4];
    #pragma unroll
    for (int s = 0; s < 4; s++) qf[s] = *(const bf16x8*)&qr[s * 16 + hi * 8];

    const float sbr = ws[WS_SBI + qrow];
    const float* adjr = adj + (size_t)qrow * N;

    f32x16 acc[2];
    #pragma unroll
    for (int hb = 0; hb < 2; hb++)
        #pragma unroll
        for (int i = 0; i < 16; i++) acc[hb][i] = 0.0f;
    float den = 0.0f;

    // prefetch step-0 adj (32 cols) into registers
    f32x4 av[4];
    #pragma unroll
    for (int c2 = 0; c2 < 4; c2++)
        av[c2] = *(const f32x4*)&adjr[j0 + c2 * 8 + hi * 4];

    uint4 rk0, rk1, rm0, rm1;

    for (int t = 0; t < NTILE; t++) {
        const int cur = t & 1;
        #pragma unroll
        for (int kb = 0; kb < 2; kb++) {
            const int colb = j0 + t * 64 + kb * 32;   // global col base of step
            const int loc  = t * 64 + kb * 32;        // within split

            // next tile's stage loads, issued first (oldest in vmcnt queue)
            if (kb == 0 && t + 1 < NTILE) {
                const int jn = j0 + (t + 1) * 64;
                rk0 = *(const uint4*)&kbp[(size_t)(jn + sr) * 64 + scb];
                rk1 = *(const uint4*)&kbp[(size_t)(jn + sr) * 64 + scb + 8];
                rm0 = *(const uint4*)&mtp[(size_t)sr * N + jn + scb];
                rm1 = *(const uint4*)&mtp[(size_t)sr * N + jn + scb + 8];
            }

            // next step's adj (stays in flight across the counted barrier)
            const bool pn = (2 * t + kb + 1 < 2 * NTILE);
            f32x4 avn[4];
            if (pn) {
                #pragma unroll
                for (int c2 = 0; c2 < 4; c2++)
                    avn[c2] = *(const f32x4*)&adjr[colb + 32 + c2 * 8 + hi * 4];
            } else {
                #pragma unroll
                for (int c2 = 0; c2 < 4; c2++) avn[c2] = av[c2];
            }

            // S^T: D[k=32][q=32] over d=64 (4 x mfma32x32x16)
            f32x16 d;
            #pragma unroll
            for (int i = 0; i < 16; i++) d[i] = 0.0f;
            #pragma unroll
            for (int s = 0; s < 4; s++) {
                const bf16x8 kf = *(const bf16x8*)&ks[cur][kb * 32 + l31][s * 16 + hi * 8];
                d = __builtin_amdgcn_mfma_f32_32x32x16_bf16(kf, qf[s], d, 0, 0, 0);
            }

            // epilogue: lane reg (4*c2+r) holds S^T[k = r + 8*c2 + 4*hi][q = l31]
            u32 wlo[4], whi[4];
            #pragma unroll
            for (int c2 = 0; c2 < 4; c2++) {
                const f32x4 sv = *(const f32x4*)&stl[loc + c2 * 8 + hi * 4];
                const f32x4 a4 = av[c2];
                const float p0 = a4[0] * __expf(fmaf(sbr, sv[0], d[c2 * 4 + 0]));
                const float p1 = a4[1] * __expf(fmaf(sbr, sv[1], d[c2 * 4 + 1]));
                const float p2 = a4[2] * __expf(fmaf(sbr, sv[2], d[c2 * 4 + 2]));
                const float p3 = a4[3] * __expf(fmaf(sbr, sv[3], d[c2 * 4 + 3]));
                den += (p0 + p1) + (p2 + p3);
                wlo[c2] = pk2(p0, p1);   // k = 8*c2+4*hi+0,1
                whi[c2] = pk2(p2, p3);   // k = 8*c2+4*hi+2,3
            }

            // P -> PV A-fragment: lane needs P[q=l31][k = s2*16 + hi*8 + 0..7].
            // Own lane has k-chunks {8c2+4hi..+3}; partner (lane^32) has the
            // 4(1-hi) chunks. One shfl_xor(32) per word + cndmask assembles it.
            bf16x8 pa[2];
            #pragma unroll
            for (int s2 = 0; s2 < 2; s2++) {
                const u32 xl0 = (u32)__shfl_xor((int)wlo[2 * s2],     32, 64);
                const u32 xh0 = (u32)__shfl_xor((int)whi[2 * s2],     32, 64);
                const u32 xl1 = (u32)__shfl_xor((int)wlo[2 * s2 + 1], 32, 64);
                const u32 xh1 = (u32)__shfl_xor((int)whi[2 * s2 + 1], 32, 64);
                const u32 f0 = hi ? xl1 : wlo[2 * s2];
                const u32 f1 = hi ? xh1 : whi[2 * s2];
                const u32 f2 = hi ? wlo[2 * s2 + 1] : xl0;
                const u32 f3 = hi ? whi[2 * s2 + 1] : xh0;
                pa[s2] = mk8(f0, f1, f2, f3);
            }

            // PV: acc[hb] += P(32q x 32k) @ M(32k x 32h)
            #pragma unroll
            for (int hb = 0; hb < 2; hb++) {
                #pragma unroll
                for (int s2 = 0; s2 < 2; s2++) {
                    const bf16x8 mf = *(const bf16x8*)
                        &ms[cur][hb * 32 + l31][kb * 32 + s2 * 16 + hi * 8];
                    acc[hb] = __builtin_amdgcn_mfma_f32_32x32x16_bf16(pa[s2], mf, acc[hb], 0, 0, 0);
                }
            }

            // deferred stage writes (write-late)
            if (kb == 1 && t + 1 < NTILE) {
                *(uint4*)&ks[cur ^ 1][sr][scb]     = rk0;
                *(uint4*)&ks[cur ^ 1][sr][scb + 8] = rk1;
                *(uint4*)&ms[cur ^ 1][sr][scb]     = rm0;
                *(uint4*)&ms[cur ^ 1][sr][scb + 8] = rm1;
            }

            #pragma unroll
            for (int c2 = 0; c2 < 4; c2++) av[c2] = avn[c2];
        }
        if (t + 1 < NTILE) TILE_BARRIER();
    }

    // agg partials: lane reg holds D[q = (reg&3)+8*(reg>>2)+4*hi][h = hb*32+l31]
    float* aggp = ws + WS_AGG + (size_t)sp * N * 64;
    #pragma unroll
    for (int hb = 0; hb < 2; hb++) {
        #pragma unroll
        for (int reg = 0; reg < 16; reg++) {
            const int qv = (reg & 3) + 8 * (reg >> 2) + 4 * hi;
            aggp[(size_t)(i0 + w * 32 + qv) * 64 + hb * 32 + l31] = acc[hb][reg];
        }
    }
    // denominator: lane halves cover complementary k-sets for the same q-row
    den += __shfl_xor(den, 32, 64);
    if (hi == 0) ws[WS_DEN + sp * N + i0 + w * 32 + l31] = den;
}

// ---------------- Kernel D: combine + LayerNorm + final MLP ----------------
__global__ __launch_bounds__(256) void final_k(
    const float* __restrict__ sa, const float* __restrict__ ln_g,
    const float* __restrict__ ln_b,
    const float* __restrict__ wa1, const float* __restrict__ ba1,
    const float* __restrict__ wa2, const float* __restrict__ ba2,
    const float* __restrict__ ws, float* __restrict__ out)
{
    const int w = threadIdx.x >> 6, lane = threadIdx.x & 63;
    const int row = blockIdx.x * 4 + w;
    __shared__ float es[4][64], hs2[4][64];
    float a = 0.0f;
    #pragma unroll
    for (int sp = 0; sp < NSPLIT; sp++)
        a += ws[WS_AGG + (size_t)sp * N * 64 + (size_t)row * 64 + lane];
    float d = 0.0f;
    #pragma unroll
    for (int sp = 0; sp < NSPLIT; sp++) d += ws[WS_DEN + sp * N + row];
    const float z = ws[WS_H + row * 64 + lane] + a / d;
    float mu = z;
    for (int off = 32; off; off >>= 1) mu += __shfl_xor(mu, off, 64);
    mu *= (1.0f / 64.0f);
    const float zc = z - mu;
    float var = zc * zc;
    for (int off = 32; off; off >>= 1) var += __shfl_xor(var, off, 64);
    var *= (1.0f / 64.0f);
    const float emb = zc * rsqrtf(var + EPSV) * ln_g[lane] + ln_b[lane];
    es[w][lane] = emb;
    __syncthreads();
    const float sa0 = sa[row * 2], sa1 = sa[row * 2 + 1];
    float hv = ba1[lane];
    #pragma unroll 8
    for (int c = 0; c < 64; c++) hv = fmaf(es[w][c], wa1[c * 64 + lane], hv);
    hv = fmaf(sa0, wa1[64 * 64 + lane], hv);
    hv = fmaf(sa1, wa1[65 * 64 + lane], hv);
    hs2[w][lane] = fmaxf(hv, 0.0f);
    __syncthreads();
    if (lane < 3) {
        float o = ba2[lane];
        for (int u = 0; u < 64; u++) o = fmaf(hs2[w][u], wa2[u * 3 + lane], o);
        out[row * 3 + lane] = o;
    }
}

extern "C" void kernel_launch(void* const* d_in, const int* in_sizes, int n_in,
                              void* d_out, int out_size, void* d_ws, size_t ws_size,
                              hipStream_t stream)
{
    const float* nf  = (const float*)d_in[0];
    const float* adj = (const float*)d_in[1];
    const float* tc  = (const float*)d_in[2];
    const float* sa  = (const float*)d_in[3];
    const float* w1  = (const float*)d_in[4];
    const float* b1  = (const float*)d_in[5];
    const float* w2  = (const float*)d_in[6];
    const float* b2  = (const float*)d_in[7];
    const float* wq  = (const float*)d_in[8];
    const float* bq  = (const float*)d_in[9];
    const float* wk  = (const float*)d_in[10];
    const float* bk  = (const float*)d_in[11];
    const float* wg  = (const float*)d_in[12];
    const float* bg  = (const float*)d_in[13];
    const float* sb  = (const float*)d_in[14];
    const float* wm  = (const float*)d_in[15];
    const float* bm  = (const float*)d_in[16];
    const float* lng = (const float*)d_in[17];
    const float* lnb = (const float*)d_in[18];
    const float* wa1 = (const float*)d_in[19];
    const float* ba1 = (const float*)d_in[20];
    const float* wa2 = (const float*)d_in[21];
    const float* ba2 = (const float*)d_in[22];
    float* ws  = (float*)d_ws;
    float* out = (float*)d_out;

    prep_k<<<1, 64, 0, stream>>>(tc, wg, bg, sb, ws + WS_SCAL);
    embed_k<<<N / 4, 256, 0, stream>>>(nf, tc, w1, b1, w2, b2, wq, bq, wk, bk,
                                       wm, bm, ws);
    transp_k<<<N / 64, 256, 0, stream>>>(ws);
    attn_k<<<dim3(N / 128, NSPLIT), 256, 0, stream>>>(adj, ws);
    final_k<<<N / 4, 256, 0, stream>>>(sa, lng, lnb, wa1, ba1, wa2, ba2, ws, out);
}